// Round 10
// baseline (238.745 us; speedup 1.0000x reference)
//
#include <hip/hip_runtime.h>
#include <hip/hip_bf16.h>
#include <stdint.h>

#define B_   4096
#define IN_  1024
#define H_   1024
#define OUT_ 1024

typedef __attribute__((ext_vector_type(8)))  short short8;
typedef __attribute__((ext_vector_type(4)))  float floatx4;
typedef __attribute__((ext_vector_type(16))) float floatx16;

// ---------- async global->LDS (16B per lane; LDS base wave-uniform, HW adds lane*16) ----------
__device__ static inline void gload_lds16(const void* g, void* l) {
    __builtin_amdgcn_global_load_lds(
        (const __attribute__((address_space(1))) unsigned int*)g,
        (__attribute__((address_space(3))) unsigned int*)l,
        16, 0, 0);
}

__device__ static inline float sigmoidf_(float x) { return 1.0f / (1.0f + __expf(-x)); }
__device__ static inline float tanhf_(float x)    { return 1.0f - 2.0f / (1.0f + __expf(2.0f * x)); }

// ---------- merged conversion kernel (R12: Wc interleave period 64) ----------
struct Ptrs8 { const float* p[8]; };

__global__ __launch_bounds__(256) void cvt_all_kernel(
        const float* __restrict__ x, const float* __restrict__ h,
        Ptrs8 ptrs, const float* __restrict__ wout,
        __hip_bfloat16* __restrict__ xh,
        __hip_bfloat16* __restrict__ Wc,
        __hip_bfloat16* __restrict__ Wob) {
    const int nth = gridDim.x * blockDim.x;
    for (int g = blockIdx.x * blockDim.x + threadIdx.x; g < 2228224; g += nth) {
        const float* src;
        __hip_bfloat16* dst;
        if (g < 1048576) {
            int b  = g >> 8;
            int c8 = (g & 255) * 8;
            src = (c8 < IN_) ? (x + (size_t)b * IN_ + c8)
                             : (h + (size_t)b * H_ + (c8 - IN_));
            dst = xh + (size_t)b * 2048 + c8;
        } else if (g < 2097152) {
            int gg = g - 1048576;
            int n  = gg >> 8;
            int c8 = (gg & 255) * 8;
            int gate = (n >> 4) & 3;
            int hh   = ((n >> 6) << 4) + (n & 15);
            src = (c8 < 1024) ? (ptrs.p[2 * gate]     + (size_t)hh * 1024 + c8)
                              : (ptrs.p[2 * gate + 1] + (size_t)hh * 1024 + (c8 - 1024));
            dst = Wc + (size_t)n * 2048 + c8;
        } else {
            int gg = g - 2097152;
            src = wout + (size_t)gg * 8;
            dst = Wob + (size_t)gg * 8;
        }
        float4 v0 = *(const float4*)src;
        float4 v1 = *(const float4*)(src + 4);
        __hip_bfloat16 tmp[8];
        tmp[0] = __float2bfloat16(v0.x);
        tmp[1] = __float2bfloat16(v0.y);
        tmp[2] = __float2bfloat16(v0.z);
        tmp[3] = __float2bfloat16(v0.w);
        tmp[4] = __float2bfloat16(v1.x);
        tmp[5] = __float2bfloat16(v1.y);
        tmp[6] = __float2bfloat16(v1.z);
        tmp[7] = __float2bfloat16(v1.w);
        *(uint4*)dst = *(const uint4*)tmp;
    }
}

// ---------- gate GEMM + fused LSTM epilogue — R13: m201 port at FULL vmcnt depth ----------
// R12 post-mortem: conflicts 0 but MfmaUtil 34% — the vmcnt(4) ledger retired loads
// issued the SAME/previous phase (~150-300 cyc lead): effectively drain-to-zero at
// P4/P8. m201's spec: 3 half-tiles in flight, vmcnt(6), retired loads have >=3-phase
// (~900 cyc) lead — T4 depth is the proven +38-73% lever (m218).
// Read windows: B0* read P1-P2 -> writable P3; A0* read P1-P3 -> writable P4;
// B1* read P5-P6 -> writable P7; A1* read P5-P7 -> writable P8.
// Stage slots: P1:A1h1(t1) P3:B0h0(t2) P4:B0h1+A0h0(t2) P5:A0h1(t2)
//              P7:B1h0(t3) P8:B1h1+A1h0(t3).  VM6 at P4/P8 after MFMA.
// FIFO @P4 (2 loads/STG): [B1h0,B1h1,A1h0 (prev), A1h1@P1, B0h0@P3, B0h1,A0h0@P4]=14
//   -> vmcnt(6) retires all of dbuf1 (needed P5-P8), keeps newest 3 half-tiles.
// FIFO @P8: [B0h0,B0h1,A0h0,A0h1, B1h0, B1h1,A1h0]=14 -> retires dbuf0 (needed next
//   P1-P4), keeps 3. Prologue: tile0 (4 halves) + tile1 {B1h0,B1h1,A1h0}, vmcnt(6).
// Tail: t2=32/t3=33 garbage tiles staged unconditionally (addresses inside ws).
__global__ __launch_bounds__(512, 2) void gemm_gate_fused(
    const __hip_bfloat16* __restrict__ A,
    const __hip_bfloat16* __restrict__ Bm,
    const float* __restrict__ cell,
    const float* __restrict__ bxf, const float* __restrict__ bxi,
    const float* __restrict__ bxo, const float* __restrict__ bxg,
    float* __restrict__ new_hidden, float* __restrict__ new_cell,
    __hip_bfloat16* __restrict__ hb)
{
    constexpr int K = 2048;

    __shared__ short A0h0[8192];  // dbuf0 A rows   0..127 (even tiles)
    __shared__ short A0h1[8192];  // dbuf0 A rows 128..255
    __shared__ short B0h0[8192];
    __shared__ short B0h1[8192];
    __shared__ short A1h0[8192];  // dbuf1 (odd tiles)
    __shared__ short A1h1[8192];
    __shared__ short B1h0[8192];
    __shared__ short B1h1[8192];

    const int tid  = threadIdx.x;
    const int lane = tid & 63;
    const int wv   = tid >> 6;      // 0..7
    const int wm   = wv >> 2;       // 0..1: row half (128 rows)
    const int wn   = wv & 3;        // 0..3: col band (64 cols)

    const int bid    = blockIdx.x;
    const int xcd    = bid & 7;
    const int loc    = bid >> 3;
    const int n_tile = xcd * 2 + (loc & 1);
    const int m_tile = loc >> 1;
    const int m0 = m_tile * 256;
    const int n0 = n_tile * 256;

    const int srow   = tid >> 3;    // 0..63
    const int scg    = (tid & 7) ^ (srow & 7);
    const __hip_bfloat16* Ag = A  + (size_t)(m0 + srow) * K + scg * 8;
    const __hip_bfloat16* Bg = Bm + (size_t)(n0 + srow) * K + scg * 8;
    const int wvoff = wv * 1024;

    const int fr16 = lane & 15;
    const int q    = lane >> 4;
    const int frb  = fr16 * 128;
    const int bb   = (wn & 1) * 8192;
    int ck[2];
    #pragma unroll
    for (int ks = 0; ks < 2; ++ks) ck[ks] = (((ks * 4 + q) ^ (lane & 7)) << 4);

    const short* myA0 = wm ? A0h1 : A0h0;
    const short* myA1 = wm ? A1h1 : A1h0;
    const short* myB0 = (wn >> 1) ? B0h1 : B0h0;
    const short* myB1 = (wn >> 1) ? B1h1 : B1h0;

    short8  fA[4][2];
    short8  fB[4][2];
    floatx4 acc[8][4] = {};

#define STG_A(DST, hh, t) do {                                                            \
    gload_lds16(Ag + (size_t)((hh)*128 +  0) * K + (size_t)(t) * 64,                      \
                (char*)(DST) + 0 * 8192 + wvoff);                                         \
    gload_lds16(Ag + (size_t)((hh)*128 + 64) * K + (size_t)(t) * 64,                      \
                (char*)(DST) + 1 * 8192 + wvoff);                                         \
} while (0)
#define STG_B(DST, hh, t) do {                                                            \
    gload_lds16(Bg + (size_t)((hh)*128 +  0) * K + (size_t)(t) * 64,                      \
                (char*)(DST) + 0 * 8192 + wvoff);                                         \
    gload_lds16(Bg + (size_t)((hh)*128 + 64) * K + (size_t)(t) * 64,                      \
                (char*)(DST) + 1 * 8192 + wvoff);                                         \
} while (0)
#define READ_A(ARR, mh) do {                                                              \
    _Pragma("unroll") for (int i = 0; i < 4; ++i)                                         \
    _Pragma("unroll") for (int ks = 0; ks < 2; ++ks)                                      \
        fA[i][ks] = *(const short8*)((const char*)(ARR) + (mh)*8192 + i*2048 + frb + ck[ks]); \
} while (0)
#define READ_B(ARR, nh) do {                                                              \
    _Pragma("unroll") for (int jj = 0; jj < 2; ++jj)                                      \
    _Pragma("unroll") for (int ks = 0; ks < 2; ++ks)                                      \
        fB[(nh)*2+jj][ks] = *(const short8*)((const char*)(ARR) + bb + ((nh)*2+jj)*2048 + frb + ck[ks]); \
} while (0)
#define MFMA_Q(mh, nh) do {                                                               \
    __builtin_amdgcn_s_setprio(1);                                                        \
    _Pragma("unroll") for (int i = 0; i < 4; ++i)                                         \
    _Pragma("unroll") for (int jj = 0; jj < 2; ++jj)                                      \
    _Pragma("unroll") for (int ks = 0; ks < 2; ++ks)                                      \
        acc[(mh)*4+i][(nh)*2+jj] = __builtin_amdgcn_mfma_f32_16x16x32_bf16(               \
            fA[i][ks], fB[(nh)*2+jj][ks], acc[(mh)*4+i][(nh)*2+jj], 0, 0, 0);             \
    __builtin_amdgcn_s_setprio(0);                                                        \
} while (0)
#define BAR __builtin_amdgcn_s_barrier()
#define VM6 asm volatile("s_waitcnt vmcnt(6)" ::: "memory")
#define LK8 asm volatile("s_waitcnt lgkmcnt(8)" ::: "memory")

    // ---- prologue: tile0 (4 half-tiles) + tile1 {B1h0,B1h1,A1h0}; retire tile0 ----
    STG_B(B0h0, 0, 0); STG_B(B0h1, 1, 0);
    STG_A(A0h0, 0, 0); STG_A(A0h1, 1, 0);
    STG_B(B1h0, 0, 1); STG_B(B1h1, 1, 1); STG_A(A1h0, 0, 1);
    VM6;                       // retire tile0; keep B1h0,B1h1,A1h0 in flight
    BAR;

    #pragma unroll 1
    for (int it = 0; it < 16; ++it) {
        const int t1 = 2 * it + 1;
        const int t2 = 2 * it + 2;   // at it=15: garbage tiles 32,33 (never read)
        const int t3 = 2 * it + 3;

        // P1
        READ_A(myA0, 0); READ_B(myB0, 0);
        STG_A(A1h1, 1, t1);
        LK8;
        BAR; MFMA_Q(0, 0); BAR;
        // P2
        READ_B(myB0, 1);
        BAR; MFMA_Q(0, 1); BAR;
        // P3
        READ_A(myA0, 1);
        STG_B(B0h0, 0, t2);
        BAR; MFMA_Q(1, 0); BAR;
        // P4
        STG_B(B0h1, 1, t2); STG_A(A0h0, 0, t2);
        BAR; MFMA_Q(1, 1); VM6; BAR;
        // P5
        READ_A(myA1, 0); READ_B(myB1, 0);
        STG_A(A0h1, 1, t2);
        LK8;
        BAR; MFMA_Q(0, 0); BAR;
        // P6
        READ_B(myB1, 1);
        BAR; MFMA_Q(0, 1); BAR;
        // P7
        READ_A(myA1, 1);
        STG_B(B1h0, 0, t3);
        BAR; MFMA_Q(1, 0); BAR;
        // P8
        STG_B(B1h1, 1, t3); STG_A(A1h0, 0, t3);
        BAR; MFMA_Q(1, 1); VM6; BAR;
    }

#undef STG_A
#undef STG_B
#undef READ_A
#undef READ_B
#undef MFMA_Q
#undef BAR
#undef VM6
#undef LK8

    // fused LSTM epilogue. C/D 16x16: col = lane&15, row = (lane>>4)*4 + reg.
    // Wave 64-col band = one gate period (16-col gate blocks) -> frag n == gate.
    const int hcol = ((n0 + wn * 64) >> 2) + fr16;
    const float bfb = bxf[hcol];
    const float bib = bxi[hcol];
    const float bob = bxo[hcol];
    const float bgb = bxg[hcol];

    #pragma unroll
    for (int m = 0; m < 8; ++m) {
        const int row_base = m0 + wm * 128 + m * 16 + q * 4;
        #pragma unroll
        for (int reg = 0; reg < 4; ++reg) {
            const int row = row_base + reg;
            const size_t off = (size_t)row * H_ + hcol;
            const float f  = sigmoidf_(acc[m][0][reg] + bfb);
            const float ii = sigmoidf_(acc[m][1][reg] + bib);
            const float o  = sigmoidf_(acc[m][2][reg] + bob);
            const float g  = tanhf_(acc[m][3][reg] + bgb);
            const float c  = f * cell[off] + ii * g;
            const float nh = o * tanhf_(c);
            new_cell[off]   = c;
            new_hidden[off] = nh;
            hb[off] = __float2bfloat16(nh);
        }
    }
}

// ---------- output GEMM (R11 pipelined version, unchanged) ----------
__global__ __launch_bounds__(256, 2) void gemm_out(
    const __hip_bfloat16* __restrict__ A,
    const __hip_bfloat16* __restrict__ Bm,
    float* __restrict__ C,
    const float* __restrict__ bias)
{
    constexpr int K  = 1024;
    constexpr int N  = 1024;

    __shared__ short oA0[8192];
    __shared__ short oB0[4096];
    __shared__ short oA1[8192];
    __shared__ short oB1[4096];

    const int tid  = threadIdx.x;
    const int lane = tid & 63;
    const int wv   = tid >> 6;

    const int bid    = blockIdx.x;
    const int xcd    = bid & 7;
    const int loc    = bid >> 3;
    const int n_tile = xcd * 2 + (loc & 1);
    const int m_tile = loc >> 1;
    const int m0 = m_tile * 128;
    const int n0 = n_tile * 64;

    const int srow   = tid >> 3;
    const int schunk = tid & 7;
    const int scg    = schunk ^ (srow & 7);
    const __hip_bfloat16* Ag = A  + (size_t)(m0 + srow) * K + scg * 8;
    const __hip_bfloat16* Bg = Bm + (size_t)(n0 + srow) * K + scg * 8;
    const int wvoff = wv * 1024;

    const int wrow  = wv * 32;
    const int fr    = lane & 31;
    const int khalf = lane >> 5;
    const int sw    = fr & 7;

    const int offA = (wrow + fr) * 128;
    int offB[2];
    #pragma unroll
    for (int j = 0; j < 2; ++j) offB[j] = (j * 32 + fr) * 128;
    const int swA = (wrow + fr) & 7;

    floatx16 acc[2] = {};

    #pragma unroll
    for (int s = 0; s < 4; ++s)
        gload_lds16(Ag + (size_t)(s * 32) * K, (char*)oA0 + s * 4096 + wvoff);
    #pragma unroll
    for (int s = 0; s < 2; ++s)
        gload_lds16(Bg + (size_t)(s * 32) * K, (char*)oB0 + s * 4096 + wvoff);

#define OTILE_BODY(RA, RB, WA, WB, k_next, DO_STAGE)                                      \
    {                                                                                     \
        __builtin_amdgcn_s_barrier();                                                     \
        if (DO_STAGE) {                                                                   \
            _Pragma("unroll")                                                             \
            for (int s = 0; s < 4; ++s)                                                   \
                gload_lds16(Ag + (size_t)(s * 32) * K + (k_next),                         \
                            (char*)(WA) + s * 4096 + wvoff);                              \
            _Pragma("unroll")                                                             \
            for (int s = 0; s < 2; ++s)                                                   \
                gload_lds16(Bg + (size_t)(s * 32) * K + (k_next),                         \
                            (char*)(WB) + s * 4096 + wvoff);                              \
            asm volatile("s_waitcnt vmcnt(6)" ::: "memory");                              \
        } else {                                                                          \
            asm volatile("s_waitcnt vmcnt(0)" ::: "memory");                              \
        }                                                                                 \
        __builtin_amdgcn_s_barrier();                                                     \
        __builtin_amdgcn_sched_barrier(0);                                                \
        _Pragma("unroll")                                                                 \
        for (int kk = 0; kk < 4; ++kk) {                                                  \
            const int cg = kk * 2 + khalf;                                                \
            short8 af = *(const short8*)((const char*)(RA) + offA + ((cg ^ swA) * 16));   \
            short8 bf[2];                                                                 \
            _Pragma("unroll")                                                             \
            for (int j = 0; j < 2; ++j)                                                   \
                bf[j] = *(const short8*)((const char*)(RB) + offB[j] + ((cg ^ sw) * 16)); \
            __builtin_amdgcn_s_setprio(1);                                                \
            _Pragma("unroll")                                                             \
            for (int j = 0; j < 2; ++j)                                                   \
                acc[j] = __builtin_amdgcn_mfma_f32_32x32x16_bf16(af, bf[j], acc[j], 0, 0, 0); \
            __builtin_amdgcn_s_setprio(0);                                                \
        }                                                                                 \
    }

    #pragma unroll 1
    for (int t2 = 0; t2 < 8; ++t2) {
        OTILE_BODY(oA0, oB0, oA1, oB1, (2 * t2 + 1) * 64, true);
        OTILE_BODY(oA1, oB1, oA0, oB0, (2 * t2 + 2) * 64, (t2 < 7));
    }
#undef OTILE_BODY

    #pragma unroll
    for (int j = 0; j < 2; ++j) {
        const int col = n0 + j * 32 + fr;
        const float bb = bias[col];
        #pragma unroll
        for (int reg = 0; reg < 16; ++reg) {
            const int row = m0 + wrow + 4 * khalf + (reg & 3) + 8 * (reg >> 2);
            C[(size_t)row * N + col] = acc[j][reg] + bb;
        }
    }
}

// ---------- launch ----------
extern "C" void kernel_launch(void* const* d_in, const int* in_sizes, int n_in,
                              void* d_out, int out_size, void* d_ws, size_t ws_size,
                              hipStream_t stream) {
    const float* input_vec  = (const float*)d_in[0];
    const float* hidden_vec = (const float*)d_in[1];
    const float* cell_vec   = (const float*)d_in[2];
    const float* Wx_f = (const float*)d_in[3];
    const float* bx_f = (const float*)d_in[4];
    const float* Wh_f = (const float*)d_in[5];
    const float* Wx_i = (const float*)d_in[6];
    const float* bx_i = (const float*)d_in[7];
    const float* Wh_i = (const float*)d_in[8];
    const float* Wx_o = (const float*)d_in[9];
    const float* bx_o = (const float*)d_in[10];
    const float* Wh_o = (const float*)d_in[11];
    const float* Wx_g = (const float*)d_in[12];
    const float* bx_g = (const float*)d_in[13];
    const float* Wh_g = (const float*)d_in[14];
    const float* W_out = (const float*)d_in[15];
    const float* b_out = (const float*)d_in[16];

    char* ws = (char*)d_ws;
    __hip_bfloat16* xh  = (__hip_bfloat16*)(ws);                        // 16 MB [4096][2048]
    __hip_bfloat16* Wc  = (__hip_bfloat16*)(ws + (16ull << 20));        // 16 MB [4096][2048]
    __hip_bfloat16* Wob = (__hip_bfloat16*)(ws + (32ull << 20));        //  2 MB [1024][1024]
    __hip_bfloat16* hb  = (__hip_bfloat16*)(ws + (34ull << 20));        //  8 MB [4096][1024]

    float* new_hidden = (float*)d_out;
    float* new_cell   = new_hidden + (size_t)B_ * H_;
    float* out_vec    = new_cell + (size_t)B_ * H_;

    Ptrs8 p;
    p.p[0] = Wx_f; p.p[1] = Wh_f; p.p[2] = Wx_i; p.p[3] = Wh_i;
    p.p[4] = Wx_o; p.p[5] = Wh_o; p.p[6] = Wx_g; p.p[7] = Wh_g;
    cvt_all_kernel<<<2048, 256, 0, stream>>>(input_vec, hidden_vec, p, W_out, xh, Wc, Wob);

    // gates GEMM + fused gating: writes new_hidden, new_cell (fp32) and hb (bf16)
    gemm_gate_fused<<<256, 512, 0, stream>>>(
        xh, Wc, cell_vec, bx_f, bx_i, bx_o, bx_g, new_hidden, new_cell, hb);

    // output_vec = new_hidden @ W_out^T + b_out
    gemm_out<<<512, 256, 0, stream>>>(hb, Wob, out_vec, b_out);
}

// Round 11
// 232.817 us; speedup vs baseline: 1.0255x; 1.0255x over previous
//
#include <hip/hip_runtime.h>
#include <hip/hip_bf16.h>
#include <stdint.h>

#define B_   4096
#define IN_  1024
#define H_   1024
#define OUT_ 1024

typedef __attribute__((ext_vector_type(8)))  short short8;
typedef __attribute__((ext_vector_type(4)))  float floatx4;
typedef __attribute__((ext_vector_type(16))) float floatx16;

// ---------- async global->LDS (16B per lane; LDS base wave-uniform, HW adds lane*16) ----------
__device__ static inline void gload_lds16(const void* g, void* l) {
    __builtin_amdgcn_global_load_lds(
        (const __attribute__((address_space(1))) unsigned int*)g,
        (__attribute__((address_space(3))) unsigned int*)l,
        16, 0, 0);
}

__device__ static inline float sigmoidf_(float x) { return 1.0f / (1.0f + __expf(-x)); }
__device__ static inline float tanhf_(float x)    { return 1.0f - 2.0f / (1.0f + __expf(2.0f * x)); }

// ---------- merged conversion kernel (R12: Wc interleave period 64) ----------
struct Ptrs8 { const float* p[8]; };

__global__ __launch_bounds__(256) void cvt_all_kernel(
        const float* __restrict__ x, const float* __restrict__ h,
        Ptrs8 ptrs, const float* __restrict__ wout,
        __hip_bfloat16* __restrict__ xh,
        __hip_bfloat16* __restrict__ Wc,
        __hip_bfloat16* __restrict__ Wob) {
    const int nth = gridDim.x * blockDim.x;
    for (int g = blockIdx.x * blockDim.x + threadIdx.x; g < 2228224; g += nth) {
        const float* src;
        __hip_bfloat16* dst;
        if (g < 1048576) {
            int b  = g >> 8;
            int c8 = (g & 255) * 8;
            src = (c8 < IN_) ? (x + (size_t)b * IN_ + c8)
                             : (h + (size_t)b * H_ + (c8 - IN_));
            dst = xh + (size_t)b * 2048 + c8;
        } else if (g < 2097152) {
            int gg = g - 1048576;
            int n  = gg >> 8;
            int c8 = (gg & 255) * 8;
            int gate = (n >> 4) & 3;
            int hh   = ((n >> 6) << 4) + (n & 15);
            src = (c8 < 1024) ? (ptrs.p[2 * gate]     + (size_t)hh * 1024 + c8)
                              : (ptrs.p[2 * gate + 1] + (size_t)hh * 1024 + (c8 - 1024));
            dst = Wc + (size_t)n * 2048 + c8;
        } else {
            int gg = g - 2097152;
            src = wout + (size_t)gg * 8;
            dst = Wob + (size_t)gg * 8;
        }
        float4 v0 = *(const float4*)src;
        float4 v1 = *(const float4*)(src + 4);
        __hip_bfloat16 tmp[8];
        tmp[0] = __float2bfloat16(v0.x);
        tmp[1] = __float2bfloat16(v0.y);
        tmp[2] = __float2bfloat16(v0.z);
        tmp[3] = __float2bfloat16(v0.w);
        tmp[4] = __float2bfloat16(v1.x);
        tmp[5] = __float2bfloat16(v1.y);
        tmp[6] = __float2bfloat16(v1.z);
        tmp[7] = __float2bfloat16(v1.w);
        *(uint4*)dst = *(const uint4*)tmp;
    }
}

// ---------- gate GEMM + fused LSTM epilogue — R12 (measured best: 80.9 us) — REVERT ----------
// R13 post-mortem: deeper vmcnt ledger + lgkmcnt pre-waits REGRESSED (87.2). This is the
// exact Round-9 R12 code: m201 8-phase template, 256x256 tile, BK=64, 8 waves 2Mx4N,
// 16x16x32 MFMA, acc[8][4], 8 static 16KB LDS arrays, vmcnt(4) at P4/P8, conflicts = 0.
__global__ __launch_bounds__(512, 2) void gemm_gate_fused(
    const __hip_bfloat16* __restrict__ A,
    const __hip_bfloat16* __restrict__ Bm,
    const float* __restrict__ cell,
    const float* __restrict__ bxf, const float* __restrict__ bxi,
    const float* __restrict__ bxo, const float* __restrict__ bxg,
    float* __restrict__ new_hidden, float* __restrict__ new_cell,
    __hip_bfloat16* __restrict__ hb)
{
    constexpr int K = 2048;

    __shared__ short A0h0[8192];  // dbuf0 A rows   0..127 (even tiles)
    __shared__ short A0h1[8192];  // dbuf0 A rows 128..255
    __shared__ short B0h0[8192];  // dbuf0 B rows   0..127
    __shared__ short B0h1[8192];  // dbuf0 B rows 128..255
    __shared__ short A1h0[8192];  // dbuf1 (odd tiles)
    __shared__ short A1h1[8192];
    __shared__ short B1h0[8192];
    __shared__ short B1h1[8192];

    const int tid  = threadIdx.x;
    const int lane = tid & 63;
    const int wv   = tid >> 6;      // 0..7
    const int wm   = wv >> 2;       // 0..1: row half (128 rows)
    const int wn   = wv & 3;        // 0..3: col band (64 cols)

    // 256 blocks = 1/CU. XCD swizzle.
    const int bid    = blockIdx.x;
    const int xcd    = bid & 7;
    const int loc    = bid >> 3;
    const int n_tile = xcd * 2 + (loc & 1);
    const int m_tile = loc >> 1;
    const int m0 = m_tile * 256;
    const int n0 = n_tile * 256;

    // staging: thread tid fills LDS slot tid*16 (wave-uniform base + lane*16);
    // row = (tid>>3) + s*64 within the 128-row half; source chunk XOR-swizzled.
    const int srow   = tid >> 3;    // 0..63
    const int scg    = (tid & 7) ^ (srow & 7);
    const __hip_bfloat16* Ag = A  + (size_t)(m0 + srow) * K + scg * 8;
    const __hip_bfloat16* Bg = Bm + (size_t)(n0 + srow) * K + scg * 8;
    const int wvoff = wv * 1024;

    // fragment read addressing (16x16x32): lane l: row = base + (l&15),
    // k-bytes 16 at quarter q=(l>>4); swizzled chunk = (ks*4+q) ^ (l&7).
    const int fr16 = lane & 15;
    const int q    = lane >> 4;
    const int frb  = fr16 * 128;
    const int bb   = (wn & 1) * 8192;   // col sub-band within B half
    int ck[2];
    #pragma unroll
    for (int ks = 0; ks < 2; ++ks) ck[ks] = (((ks * 4 + q) ^ (lane & 7)) << 4);

    const short* myA0 = wm ? A0h1 : A0h0;
    const short* myA1 = wm ? A1h1 : A1h0;
    const short* myB0 = (wn >> 1) ? B0h1 : B0h0;
    const short* myB1 = (wn >> 1) ? B1h1 : B1h0;

    short8  fA[4][2];   // current M-quadrant: 4 m-frags x 2 k-slices
    short8  fB[4][2];   // all 4 n-frags x 2 k-slices (live across the tile)
    floatx4 acc[8][4] = {};

#define STG_A(DST, hh, t) do {                                                            \
    gload_lds16(Ag + (size_t)((hh)*128 +  0) * K + (size_t)(t) * 64,                      \
                (char*)(DST) + 0 * 8192 + wvoff);                                         \
    gload_lds16(Ag + (size_t)((hh)*128 + 64) * K + (size_t)(t) * 64,                      \
                (char*)(DST) + 1 * 8192 + wvoff);                                         \
} while (0)
#define STG_B(DST, hh, t) do {                                                            \
    gload_lds16(Bg + (size_t)((hh)*128 +  0) * K + (size_t)(t) * 64,                      \
                (char*)(DST) + 0 * 8192 + wvoff);                                         \
    gload_lds16(Bg + (size_t)((hh)*128 + 64) * K + (size_t)(t) * 64,                      \
                (char*)(DST) + 1 * 8192 + wvoff);                                         \
} while (0)
#define READ_A(ARR, mh) do {                                                              \
    _Pragma("unroll") for (int i = 0; i < 4; ++i)                                         \
    _Pragma("unroll") for (int ks = 0; ks < 2; ++ks)                                      \
        fA[i][ks] = *(const short8*)((const char*)(ARR) + (mh)*8192 + i*2048 + frb + ck[ks]); \
} while (0)
#define READ_B(ARR, nh) do {                                                              \
    _Pragma("unroll") for (int jj = 0; jj < 2; ++jj)                                      \
    _Pragma("unroll") for (int ks = 0; ks < 2; ++ks)                                      \
        fB[(nh)*2+jj][ks] = *(const short8*)((const char*)(ARR) + bb + ((nh)*2+jj)*2048 + frb + ck[ks]); \
} while (0)
#define MFMA_Q(mh, nh) do {                                                               \
    __builtin_amdgcn_s_setprio(1);                                                        \
    _Pragma("unroll") for (int i = 0; i < 4; ++i)                                         \
    _Pragma("unroll") for (int jj = 0; jj < 2; ++jj)                                      \
    _Pragma("unroll") for (int ks = 0; ks < 2; ++ks)                                      \
        acc[(mh)*4+i][(nh)*2+jj] = __builtin_amdgcn_mfma_f32_16x16x32_bf16(               \
            fA[i][ks], fB[(nh)*2+jj][ks], acc[(mh)*4+i][(nh)*2+jj], 0, 0, 0);             \
    __builtin_amdgcn_s_setprio(0);                                                        \
} while (0)
#define BAR __builtin_amdgcn_s_barrier()
#define VM4 asm volatile("s_waitcnt vmcnt(4)" ::: "memory")

    // ---- prologue: tile 0 (4 half-tiles) + tile 1's h0 pair; retire tile 0 ----
    STG_B(B0h0, 0, 0); STG_B(B0h1, 1, 0);
    STG_A(A0h0, 0, 0); STG_A(A0h1, 1, 0);
    STG_B(B1h0, 0, 1); STG_A(A1h0, 0, 1);
    VM4;                       // retire tile-0 half-tiles; keep B1h0,A1h0 in flight
    BAR;

    #pragma unroll 1
    for (int it = 0; it < 16; ++it) {
        const int t1 = 2 * it + 1;
        const int t2 = 2 * it + 2;   // at it=15: garbage tiles 32,33 (never read)
        const int t3 = 2 * it + 3;

        // P1
        READ_A(myA0, 0); READ_B(myB0, 0);
        STG_B(B1h1, 1, t1);
        BAR; MFMA_Q(0, 0); BAR;
        // P2
        READ_B(myB0, 1);
        STG_A(A1h1, 1, t1);
        BAR; MFMA_Q(0, 1); BAR;
        // P3
        READ_A(myA0, 1);
        STG_B(B0h0, 0, t2);
        BAR; MFMA_Q(1, 0); BAR;
        // P4
        STG_B(B0h1, 1, t2);
        BAR; MFMA_Q(1, 1); VM4; BAR;
        // P5
        READ_A(myA1, 0); READ_B(myB1, 0);
        STG_A(A0h0, 0, t2);
        BAR; MFMA_Q(0, 0); BAR;
        // P6
        READ_B(myB1, 1);
        STG_A(A0h1, 1, t2);
        BAR; MFMA_Q(0, 1); BAR;
        // P7
        READ_A(myA1, 1);
        STG_B(B1h0, 0, t3);
        BAR; MFMA_Q(1, 0); BAR;
        // P8
        STG_A(A1h0, 0, t3);
        BAR; MFMA_Q(1, 1); VM4; BAR;
    }

#undef STG_A
#undef STG_B
#undef READ_A
#undef READ_B
#undef MFMA_Q
#undef BAR
#undef VM4

    // fused LSTM epilogue. C/D 16x16 layout: col = lane&15, row = (lane>>4)*4 + reg.
    // Wave cols n0+wn*64..+64 = one gate period (16-col gate blocks) -> frag index
    // n == gate; lane owns all 4 gates of h = (n0+wn*64)/4 + (lane&15).
    const int hcol = ((n0 + wn * 64) >> 2) + fr16;
    const float bfb = bxf[hcol];
    const float bib = bxi[hcol];
    const float bob = bxo[hcol];
    const float bgb = bxg[hcol];

    #pragma unroll
    for (int m = 0; m < 8; ++m) {
        const int row_base = m0 + wm * 128 + m * 16 + q * 4;
        #pragma unroll
        for (int reg = 0; reg < 4; ++reg) {
            const int row = row_base + reg;
            const size_t off = (size_t)row * H_ + hcol;
            const float f  = sigmoidf_(acc[m][0][reg] + bfb);
            const float ii = sigmoidf_(acc[m][1][reg] + bib);
            const float o  = sigmoidf_(acc[m][2][reg] + bob);
            const float g  = tanhf_(acc[m][3][reg] + bgb);
            const float c  = f * cell[off] + ii * g;
            const float nh = o * tanhf_(c);
            new_cell[off]   = c;
            new_hidden[off] = nh;
            hb[off] = __float2bfloat16(nh);
        }
    }
}

// ---------- output GEMM (R11 pipelined version, unchanged) ----------
__global__ __launch_bounds__(256, 2) void gemm_out(
    const __hip_bfloat16* __restrict__ A,
    const __hip_bfloat16* __restrict__ Bm,
    float* __restrict__ C,
    const float* __restrict__ bias)
{
    constexpr int K  = 1024;
    constexpr int N  = 1024;

    __shared__ short oA0[8192];
    __shared__ short oB0[4096];
    __shared__ short oA1[8192];
    __shared__ short oB1[4096];

    const int tid  = threadIdx.x;
    const int lane = tid & 63;
    const int wv   = tid >> 6;

    const int bid    = blockIdx.x;
    const int xcd    = bid & 7;
    const int loc    = bid >> 3;
    const int n_tile = xcd * 2 + (loc & 1);
    const int m_tile = loc >> 1;
    const int m0 = m_tile * 128;
    const int n0 = n_tile * 64;

    const int srow   = tid >> 3;
    const int schunk = tid & 7;
    const int scg    = schunk ^ (srow & 7);
    const __hip_bfloat16* Ag = A  + (size_t)(m0 + srow) * K + scg * 8;
    const __hip_bfloat16* Bg = Bm + (size_t)(n0 + srow) * K + scg * 8;
    const int wvoff = wv * 1024;

    const int wrow  = wv * 32;
    const int fr    = lane & 31;
    const int khalf = lane >> 5;
    const int sw    = fr & 7;

    const int offA = (wrow + fr) * 128;
    int offB[2];
    #pragma unroll
    for (int j = 0; j < 2; ++j) offB[j] = (j * 32 + fr) * 128;
    const int swA = (wrow + fr) & 7;

    floatx16 acc[2] = {};

    #pragma unroll
    for (int s = 0; s < 4; ++s)
        gload_lds16(Ag + (size_t)(s * 32) * K, (char*)oA0 + s * 4096 + wvoff);
    #pragma unroll
    for (int s = 0; s < 2; ++s)
        gload_lds16(Bg + (size_t)(s * 32) * K, (char*)oB0 + s * 4096 + wvoff);

#define OTILE_BODY(RA, RB, WA, WB, k_next, DO_STAGE)                                      \
    {                                                                                     \
        __builtin_amdgcn_s_barrier();                                                     \
        if (DO_STAGE) {                                                                   \
            _Pragma("unroll")                                                             \
            for (int s = 0; s < 4; ++s)                                                   \
                gload_lds16(Ag + (size_t)(s * 32) * K + (k_next),                         \
                            (char*)(WA) + s * 4096 + wvoff);                              \
            _Pragma("unroll")                                                             \
            for (int s = 0; s < 2; ++s)                                                   \
                gload_lds16(Bg + (size_t)(s * 32) * K + (k_next),                         \
                            (char*)(WB) + s * 4096 + wvoff);                              \
            asm volatile("s_waitcnt vmcnt(6)" ::: "memory");                              \
        } else {                                                                          \
            asm volatile("s_waitcnt vmcnt(0)" ::: "memory");                              \
        }                                                                                 \
        __builtin_amdgcn_s_barrier();                                                     \
        __builtin_amdgcn_sched_barrier(0);                                                \
        _Pragma("unroll")                                                                 \
        for (int kk = 0; kk < 4; ++kk) {                                                  \
            const int cg = kk * 2 + khalf;                                                \
            short8 af = *(const short8*)((const char*)(RA) + offA + ((cg ^ swA) * 16));   \
            short8 bf[2];                                                                 \
            _Pragma("unroll")                                                             \
            for (int j = 0; j < 2; ++j)                                                   \
                bf[j] = *(const short8*)((const char*)(RB) + offB[j] + ((cg ^ sw) * 16)); \
            __builtin_amdgcn_s_setprio(1);                                                \
            _Pragma("unroll")                                                             \
            for (int j = 0; j < 2; ++j)                                                   \
                acc[j] = __builtin_amdgcn_mfma_f32_32x32x16_bf16(af, bf[j], acc[j], 0, 0, 0); \
            __builtin_amdgcn_s_setprio(0);                                                \
        }                                                                                 \
    }

    #pragma unroll 1
    for (int t2 = 0; t2 < 8; ++t2) {
        OTILE_BODY(oA0, oB0, oA1, oB1, (2 * t2 + 1) * 64, true);
        OTILE_BODY(oA1, oB1, oA0, oB0, (2 * t2 + 2) * 64, (t2 < 7));
    }
#undef OTILE_BODY

    #pragma unroll
    for (int j = 0; j < 2; ++j) {
        const int col = n0 + j * 32 + fr;
        const float bb = bias[col];
        #pragma unroll
        for (int reg = 0; reg < 16; ++reg) {
            const int row = m0 + wrow + 4 * khalf + (reg & 3) + 8 * (reg >> 2);
            C[(size_t)row * N + col] = acc[j][reg] + bb;
        }
    }
}

// ---------- launch ----------
extern "C" void kernel_launch(void* const* d_in, const int* in_sizes, int n_in,
                              void* d_out, int out_size, void* d_ws, size_t ws_size,
                              hipStream_t stream) {
    const float* input_vec  = (const float*)d_in[0];
    const float* hidden_vec = (const float*)d_in[1];
    const float* cell_vec   = (const float*)d_in[2];
    const float* Wx_f = (const float*)d_in[3];
    const float* bx_f = (const float*)d_in[4];
    const float* Wh_f = (const float*)d_in[5];
    const float* Wx_i = (const float*)d_in[6];
    const float* bx_i = (const float*)d_in[7];
    const float* Wh_i = (const float*)d_in[8];
    const float* Wx_o = (const float*)d_in[9];
    const float* bx_o = (const float*)d_in[10];
    const float* Wh_o = (const float*)d_in[11];
    const float* Wx_g = (const float*)d_in[12];
    const float* bx_g = (const float*)d_in[13];
    const float* Wh_g = (const float*)d_in[14];
    const float* W_out = (const float*)d_in[15];
    const float* b_out = (const float*)d_in[16];

    char* ws = (char*)d_ws;
    __hip_bfloat16* xh  = (__hip_bfloat16*)(ws);                        // 16 MB [4096][2048]
    __hip_bfloat16* Wc  = (__hip_bfloat16*)(ws + (16ull << 20));        // 16 MB [4096][2048]
    __hip_bfloat16* Wob = (__hip_bfloat16*)(ws + (32ull << 20));        //  2 MB [1024][1024]
    __hip_bfloat16* hb  = (__hip_bfloat16*)(ws + (34ull << 20));        //  8 MB [4096][1024]

    float* new_hidden = (float*)d_out;
    float* new_cell   = new_hidden + (size_t)B_ * H_;
    float* out_vec    = new_cell + (size_t)B_ * H_;

    Ptrs8 p;
    p.p[0] = Wx_f; p.p[1] = Wh_f; p.p[2] = Wx_i; p.p[3] = Wh_i;
    p.p[4] = Wx_o; p.p[5] = Wh_o; p.p[6] = Wx_g; p.p[7] = Wh_g;
    cvt_all_kernel<<<2048, 256, 0, stream>>>(input_vec, hidden_vec, p, W_out, xh, Wc, Wob);

    // gates GEMM + fused gating: writes new_hidden, new_cell (fp32) and hb (bf16)
    gemm_gate_fused<<<256, 512, 0, stream>>>(
        xh, Wc, cell_vec, bx_f, bx_i, bx_o, bx_g, new_hidden, new_cell, hb);

    // output_vec = new_hidden @ W_out^T + b_out
    gemm_out<<<512, 256, 0, stream>>>(hb, Wob, out_vec, b_out);
}